// Round 1
// baseline (374.524 us; speedup 1.0000x reference)
//
#include <hip/hip_runtime.h>

#define B_   64
#define T_   2048
#define TM1  2047
#define D_   64

// pair index for strict lower triangle (i>j), 28 entries
#define PID(i,j) ((i)*((i)-1)/2 + (j))

__device__ __forceinline__ unsigned short f2bf(float v) {
    unsigned u = __float_as_uint(v);
    u = (u + 0x7FFFu + ((u >> 16) & 1u)) >> 16;   // round-to-nearest-even
    return (unsigned short)u;
}

// K1: dX -> Mlie -> expm (s=4, Taylor-8) -> LayerNorm -> proj(256->64), writes f_proj (B, T-1, 64)
__global__ __launch_bounds__(256, 2) void k_expm(
    const float* __restrict__ x, const float* __restrict__ mask,
    const float* __restrict__ Wd, const float* __restrict__ lng,
    const float* __restrict__ lnb, const float* __restrict__ pw,
    const float* __restrict__ pb, float* __restrict__ f_out)
{
    // region A (32KB): xT[64][65] fp32 during phase 1, then f bf16 [256][64]
    __shared__ __align__(16) unsigned char smA[256 * 64 * 2];
    __shared__ __align__(16) float pwsh[64 * 64];          // 16KB proj_w chunk
    float* xT = (float*)smA;
    unsigned short* fsh = (unsigned short*)smA;

    const int tid  = threadIdx.x;
    const int lane = tid & 63;
    const int wq   = __builtin_amdgcn_readfirstlane(tid >> 6);  // wave id = group g
    const int b    = blockIdx.x >> 5;
    const int t0   = (blockIdx.x & 31) << 6;

    // stage x[b, t0 .. t0+64, :] transposed: xT[c][r], stride 65 (conflict-free)
    const float* xb = x + (size_t)b * (T_ * D_);
    for (int idx = tid; idx < 65 * 64; idx += 256) {
        int r = idx >> 6, c = idx & 63;
        int tr = t0 + r;
        xT[c * 65 + r] = (tr < T_) ? xb[tr * 64 + c] : 0.f;
    }
    __syncthreads();

    const int t = t0 + lane;
    const bool valid = (t < TM1);
    const float mk = valid ? mask[b * T_ + t + 1] : 0.f;

    // Mlie lower triangle: A[i][j] = sum_d dx_d * W[g,d,i,j]  (i>j)
    float al[28];
    #pragma unroll
    for (int p = 0; p < 28; ++p) al[p] = 0.f;
    const float* Wg = Wd + wq * (16 * 64);
    #pragma unroll
    for (int d = 0; d < 16; ++d) {
        const float* col = &xT[(wq * 16 + d) * 65 + lane];
        float dxd = (col[1] - col[0]) * mk;
        const float* Wrow = Wg + d * 64;
        #pragma unroll
        for (int i = 1; i < 8; ++i)
            #pragma unroll
            for (int j = 0; j < i; ++j)
                al[PID(i, j)] = fmaf(dxd, Wrow[i * 8 + j], al[PID(i, j)]);
    }
    __syncthreads();   // xT dead after this point (region reused for f)

    #pragma unroll
    for (int p = 0; p < 28; ++p) al[p] *= 0.0625f;   // scale by 1/2^4

    // expm: term = As, out = I + As; Taylor k=2..8; 4 squarings
    float term[64], out[64];
    #pragma unroll
    for (int i = 0; i < 8; ++i)
        #pragma unroll
        for (int j = 0; j < 8; ++j) {
            float a0 = (i > j) ? al[PID(i, j)] : ((i < j) ? -al[PID(j, i)] : 0.f);
            term[i * 8 + j] = a0;
            out[i * 8 + j]  = a0 + ((i == j) ? 1.f : 0.f);
        }
    for (int k = 2; k <= 8; ++k) {
        float invk = 1.f / (float)k;
        #pragma unroll
        for (int i = 0; i < 8; ++i) {
            float r[8];
            #pragma unroll
            for (int j = 0; j < 8; ++j) {
                float s = 0.f;
                #pragma unroll
                for (int kk = 0; kk < 8; ++kk) {
                    if (kk == j) continue;           // A[j][j] == 0
                    float a = (kk > j) ? al[PID(kk, j)] : -al[PID(j, kk)];
                    s = fmaf(term[i * 8 + kk], a, s);
                }
                r[j] = s;
            }
            #pragma unroll
            for (int j = 0; j < 8; ++j) {
                float nt = r[j] * invk;
                term[i * 8 + j] = nt;
                out[i * 8 + j] += nt;
            }
        }
    }
    for (int sq = 0; sq < 4; ++sq) {
        float nw[64];
        #pragma unroll
        for (int i = 0; i < 8; ++i)
            #pragma unroll
            for (int j = 0; j < 8; ++j) {
                float s = 0.f;
                #pragma unroll
                for (int kk = 0; kk < 8; ++kk)
                    s = fmaf(out[i * 8 + kk], out[kk * 8 + j], s);
                nw[i * 8 + j] = s;
            }
        #pragma unroll
        for (int e = 0; e < 64; ++e) out[e] = nw[e];
    }

    // LayerNorm over the 64 elements (gamma/beta shared across groups)
    float sum = 0.f, ssq = 0.f;
    #pragma unroll
    for (int e = 0; e < 64; ++e) { sum += out[e]; ssq = fmaf(out[e], out[e], ssq); }
    float mu   = sum * (1.f / 64.f);
    float var  = ssq * (1.f / 64.f) - mu * mu;
    float rstd = rsqrtf(var + 1e-5f);

    // write LN'd f to LDS as bf16: row = g*64+e, col = lane (contiguous per row)
    #pragma unroll
    for (int e = 0; e < 64; ++e) {
        float nv = (out[e] - mu) * rstd;
        nv = fmaf(nv, lng[e], lnb[e]);
        fsh[(wq * 64 + e) * 64 + lane] = f2bf(nv);
    }

    // proj: thread (lane=position l, wq=o-slice) accumulates 16 outputs over all 256 features
    float acc[16];
    #pragma unroll
    for (int j = 0; j < 16; ++j) acc[j] = 0.f;
    for (int c = 0; c < 4; ++c) {
        __syncthreads();                           // f ready / prev chunk consumed
        for (int idx = tid; idx < 4096; idx += 256)
            pwsh[idx] = pw[c * 4096 + idx];
        __syncthreads();
        #pragma unroll 4
        for (int e = 0; e < 64; ++e) {
            float fe = __uint_as_float((unsigned)fsh[(c * 64 + e) * 64 + lane] << 16);
            const float* wr = &pwsh[e * 64 + wq * 16];
            #pragma unroll
            for (int j = 0; j < 16; ++j)
                acc[j] = fmaf(fe, wr[j], acc[j]);
        }
    }
    if (valid) {
        float* dst = f_out + ((size_t)b * TM1 + t) * 64 + wq * 16;
        #pragma unroll
        for (int j = 0; j < 16; ++j) dst[j] = acc[j] + pb[wq * 16 + j];
    }
}

// K2: pooled[b][o] = sum_t (x + interp(f)) * mask ; denom[b] = sum_t mask
__global__ void k_pool(const float* __restrict__ x, const float* __restrict__ mask,
                       const float* __restrict__ f, float* __restrict__ pooled,
                       float* __restrict__ denom)
{
    const int b  = blockIdx.x >> 3;
    const int t0 = (blockIdx.x & 7) << 8;
    const int o  = threadIdx.x & 63;
    const int tr = threadIdx.x >> 6;
    const float* xb = x + (size_t)b * (T_ * D_);
    const float* fb = f + (size_t)b * (TM1 * 64);
    float acc = 0.f, am = 0.f;
    for (int i = 0; i < 64; ++i) {
        int tt = t0 + tr + i * 4;
        float mk  = mask[b * T_ + tt];
        float pos = fminf(fmaxf((tt + 0.5f) * (2047.f / 2048.f) - 0.5f, 0.f), 2046.f);
        int   i0  = (int)pos;
        float w   = pos - (float)i0;
        int   i1  = min(i0 + 1, 2046);
        float fi  = fb[i0 * 64 + o] * (1.f - w) + fb[i1 * 64 + o] * w;
        float h1  = xb[tt * 64 + o] + fi;
        acc = fmaf(h1, mk, acc);
        am += mk;
    }
    atomicAdd(&pooled[b * 64 + o], acc);
    if (o == 0) atomicAdd(&denom[b], am);
}

// K3: SE gate s[b][o]
__global__ void k_se(const float* __restrict__ pooled, const float* __restrict__ denom,
                     const float* __restrict__ w1, const float* __restrict__ b1,
                     const float* __restrict__ w2, const float* __restrict__ b2,
                     float* __restrict__ s_out)
{
    __shared__ float pl[64];
    __shared__ float hid[4];
    const int b = blockIdx.x, o = threadIdx.x;
    float p = pooled[b * 64 + o] / denom[b];
    pl[o] = p;
    __syncthreads();
    if (o < 4) {
        float h = b1[o];
        for (int e = 0; e < 64; ++e) h = fmaf(pl[e], w1[e * 4 + o], h);
        hid[o] = 0.5f * h * (1.f + erff(h * 0.70710678118654752f));  // exact gelu
    }
    __syncthreads();
    float sv = b2[o];
    #pragma unroll
    for (int hh = 0; hh < 4; ++hh) sv = fmaf(hid[hh], w2[hh * 64 + o], sv);
    s_out[b * 64 + o] = 1.f / (1.f + expf(-sv));
}

// K4: out = (x + interp(f)) * s + x
__global__ void k_apply(const float* __restrict__ x, const float* __restrict__ f,
                        const float* __restrict__ s, float* __restrict__ out)
{
    int gid = blockIdx.x * 256 + threadIdx.x;
    int o = gid & 63;
    int t = (gid >> 6) & 2047;
    int b = gid >> 17;
    float pos = fminf(fmaxf((t + 0.5f) * (2047.f / 2048.f) - 0.5f, 0.f), 2046.f);
    int   i0  = (int)pos;
    float w   = pos - (float)i0;
    int   i1  = min(i0 + 1, 2046);
    const float* fb = f + (size_t)b * (TM1 * 64);
    float fi = fb[i0 * 64 + o] * (1.f - w) + fb[i1 * 64 + o] * w;
    float xv = x[gid];
    float h1 = xv + fi;
    out[gid] = fmaf(h1, s[b * 64 + o], xv);
}

extern "C" void kernel_launch(void* const* d_in, const int* in_sizes, int n_in,
                              void* d_out, int out_size, void* d_ws, size_t ws_size,
                              hipStream_t stream)
{
    const float* x    = (const float*)d_in[0];
    const float* mask = (const float*)d_in[1];
    const float* Wd   = (const float*)d_in[2];
    const float* lng  = (const float*)d_in[3];
    const float* lnb  = (const float*)d_in[4];
    const float* pw   = (const float*)d_in[5];
    const float* pb   = (const float*)d_in[6];
    const float* sw1  = (const float*)d_in[7];
    const float* sb1  = (const float*)d_in[8];
    const float* sw2  = (const float*)d_in[9];
    const float* sb2  = (const float*)d_in[10];

    float* out    = (float*)d_out;
    float* f_ws   = (float*)d_ws;                 // 64*2047*64 = 33,538,048 floats
    float* pooled = f_ws + (size_t)B_ * TM1 * 64; // 4096
    float* denom  = pooled + 4096;                // 64
    float* s_ws   = denom + 64;                   // 4096

    hipMemsetAsync(pooled, 0, (4096 + 64) * sizeof(float), stream);

    hipLaunchKernelGGL(k_expm, dim3(2048), dim3(256), 0, stream,
                       x, mask, Wd, lng, lnb, pw, pb, f_ws);
    hipLaunchKernelGGL(k_pool, dim3(512), dim3(256), 0, stream,
                       x, mask, f_ws, pooled, denom);
    hipLaunchKernelGGL(k_se, dim3(64), dim3(64), 0, stream,
                       pooled, denom, sw1, sb1, sw2, sb2, s_ws);
    hipLaunchKernelGGL(k_apply, dim3(32768), dim3(256), 0, stream,
                       x, f_ws, s_ws, out);

    hipMemcpyAsync(out + (size_t)B_ * T_ * D_, mask,
                   (size_t)B_ * T_ * sizeof(float), hipMemcpyDeviceToDevice, stream);
}

// Round 2
// 298.837 us; speedup vs baseline: 1.2533x; 1.2533x over previous
//
#include <hip/hip_runtime.h>

#define B_   64
#define T_   2048
#define TM1  2047
#define D_   64

// pair index for strict lower triangle (i>j), 28 entries
#define PID(i,j) ((i)*((i)-1)/2 + (j))

__device__ __forceinline__ unsigned short f2bf(float v) {
    unsigned u = __float_as_uint(v);
    u = (u + 0x7FFFu + ((u >> 16) & 1u)) >> 16;   // round-to-nearest-even
    return (unsigned short)u;
}

// K1: dX -> Mlie -> expm (s=3, Horner Taylor-9, in-place column update) -> LN -> proj(256->64)
__global__ __launch_bounds__(256, 3) void k_expm(
    const float* __restrict__ x, const float* __restrict__ mask,
    const float* __restrict__ Wd, const float* __restrict__ lng,
    const float* __restrict__ lnb, const float* __restrict__ pw,
    const float* __restrict__ pb, float* __restrict__ f_out)
{
    // region A (32KB): xT[64][65] fp32 during phase 1, then f bf16 [256][64]
    __shared__ __align__(16) unsigned char smA[256 * 64 * 2];
    __shared__ __align__(16) float pwsh[64 * 64];          // 16KB proj_w chunk
    float* xT = (float*)smA;
    unsigned short* fsh = (unsigned short*)smA;

    const int tid  = threadIdx.x;
    const int lane = tid & 63;
    const int wq   = __builtin_amdgcn_readfirstlane(tid >> 6);  // wave id = group g
    const int b    = blockIdx.x >> 5;
    const int t0   = (blockIdx.x & 31) << 6;

    // stage x[b, t0 .. t0+64, :] transposed: xT[c][r], stride 65 (conflict-free)
    const float* xb = x + (size_t)b * (T_ * D_);
    for (int idx = tid; idx < 65 * 64; idx += 256) {
        int r = idx >> 6, c = idx & 63;
        int tr = t0 + r;
        xT[c * 65 + r] = (tr < T_) ? xb[tr * 64 + c] : 0.f;
    }
    __syncthreads();

    const int t = t0 + lane;
    const bool valid = (t < TM1);
    const float mk = valid ? mask[b * T_ + t + 1] : 0.f;

    // Mlie lower triangle: A[i][j] = sum_d dx_d * W[g,d,i,j]  (i>j)
    float al[28];
    #pragma unroll
    for (int p = 0; p < 28; ++p) al[p] = 0.f;
    const float* Wg = Wd + wq * (16 * 64);
    #pragma unroll
    for (int d = 0; d < 16; ++d) {
        const float* col = &xT[(wq * 16 + d) * 65 + lane];
        float dxd = (col[1] - col[0]) * mk;
        const float* Wrow = Wg + d * 64;
        #pragma unroll
        for (int i = 1; i < 8; ++i)
            #pragma unroll
            for (int j = 0; j < i; ++j)
                al[PID(i, j)] = fmaf(dxd, Wrow[i * 8 + j], al[PID(i, j)]);
    }
    __syncthreads();   // xT dead after this point (region reused for f)

    #pragma unroll
    for (int p = 0; p < 28; ++p) al[p] *= 0.125f;   // scale by 1/2^3

    // expm via Horner: R = I; for k=9..1: R = I + (A/k)*R, updated in place
    // column-by-column (new column j depends only on old column j of R).
    float R[64];
    #pragma unroll
    for (int i = 0; i < 8; ++i)
        #pragma unroll
        for (int j = 0; j < 8; ++j)
            R[i * 8 + j] = (i == j) ? 1.f : 0.f;

    for (int k = 9; k >= 1; --k) {
        float invk = 1.f / (float)k;
        #pragma unroll
        for (int j = 0; j < 8; ++j) {
            float tmp[8];
            #pragma unroll
            for (int i = 0; i < 8; ++i) tmp[i] = R[i * 8 + j];
            #pragma unroll
            for (int i = 0; i < 8; ++i) {
                float s = 0.f;
                #pragma unroll
                for (int kk = 0; kk < 8; ++kk) {
                    if (kk == i) continue;            // A[i][i] == 0
                    float a = (i > kk) ? al[PID(i, kk)] : -al[PID(kk, i)];
                    s = fmaf(a, tmp[kk], s);
                }
                R[i * 8 + j] = ((i == j) ? 1.f : 0.f) + invk * s;
            }
        }
    }
    // 3 squarings
    for (int sq = 0; sq < 3; ++sq) {
        float nw[64];
        #pragma unroll
        for (int i = 0; i < 8; ++i)
            #pragma unroll
            for (int j = 0; j < 8; ++j) {
                float s = 0.f;
                #pragma unroll
                for (int kk = 0; kk < 8; ++kk)
                    s = fmaf(R[i * 8 + kk], R[kk * 8 + j], s);
                nw[i * 8 + j] = s;
            }
        #pragma unroll
        for (int e = 0; e < 64; ++e) R[e] = nw[e];
    }

    // LayerNorm over the 64 elements (gamma/beta shared across groups)
    float sum = 0.f, ssq = 0.f;
    #pragma unroll
    for (int e = 0; e < 64; ++e) { sum += R[e]; ssq = fmaf(R[e], R[e], ssq); }
    float mu   = sum * (1.f / 64.f);
    float var  = ssq * (1.f / 64.f) - mu * mu;
    float rstd = rsqrtf(var + 1e-5f);

    // write LN'd f to LDS as bf16: row = g*64+e, col = lane (contiguous per row)
    #pragma unroll
    for (int e = 0; e < 64; ++e) {
        float nv = (R[e] - mu) * rstd;
        nv = fmaf(nv, lng[e], lnb[e]);
        fsh[(wq * 64 + e) * 64 + lane] = f2bf(nv);
    }

    // proj: thread (lane=position l, wq=o-slice) accumulates 16 outputs over all 256 features
    float acc[16];
    #pragma unroll
    for (int j = 0; j < 16; ++j) acc[j] = 0.f;
    for (int c = 0; c < 4; ++c) {
        __syncthreads();                           // f ready / prev chunk consumed
        for (int idx = tid; idx < 4096; idx += 256)
            pwsh[idx] = pw[c * 4096 + idx];
        __syncthreads();
        #pragma unroll 4
        for (int e = 0; e < 64; ++e) {
            float fe = __uint_as_float((unsigned)fsh[(c * 64 + e) * 64 + lane] << 16);
            const float* wr = &pwsh[e * 64 + wq * 16];
            #pragma unroll
            for (int j = 0; j < 16; ++j)
                acc[j] = fmaf(fe, wr[j], acc[j]);
        }
    }
    if (valid) {
        float* dst = f_out + ((size_t)b * TM1 + t) * 64 + wq * 16;
        #pragma unroll
        for (int j = 0; j < 16; ++j) dst[j] = acc[j] + pb[wq * 16 + j];
    }
}

// K2: pooled[b][o] = sum_t (x + interp(f)) * mask ; denom[b] = sum_t mask
__global__ void k_pool(const float* __restrict__ x, const float* __restrict__ mask,
                       const float* __restrict__ f, float* __restrict__ pooled,
                       float* __restrict__ denom)
{
    const int b  = blockIdx.x >> 3;
    const int t0 = (blockIdx.x & 7) << 8;
    const int o  = threadIdx.x & 63;
    const int tr = threadIdx.x >> 6;
    const float* xb = x + (size_t)b * (T_ * D_);
    const float* fb = f + (size_t)b * (TM1 * 64);
    float acc = 0.f, am = 0.f;
    for (int i = 0; i < 64; ++i) {
        int tt = t0 + tr + i * 4;
        float mk  = mask[b * T_ + tt];
        float pos = fminf(fmaxf((tt + 0.5f) * (2047.f / 2048.f) - 0.5f, 0.f), 2046.f);
        int   i0  = (int)pos;
        float w   = pos - (float)i0;
        int   i1  = min(i0 + 1, 2046);
        float fi  = fb[i0 * 64 + o] * (1.f - w) + fb[i1 * 64 + o] * w;
        float h1  = xb[tt * 64 + o] + fi;
        acc = fmaf(h1, mk, acc);
        am += mk;
    }
    atomicAdd(&pooled[b * 64 + o], acc);
    if (o == 0) atomicAdd(&denom[b], am);
}

// K3: SE gate s[b][o]
__global__ void k_se(const float* __restrict__ pooled, const float* __restrict__ denom,
                     const float* __restrict__ w1, const float* __restrict__ b1,
                     const float* __restrict__ w2, const float* __restrict__ b2,
                     float* __restrict__ s_out)
{
    __shared__ float pl[64];
    __shared__ float hid[4];
    const int b = blockIdx.x, o = threadIdx.x;
    float p = pooled[b * 64 + o] / denom[b];
    pl[o] = p;
    __syncthreads();
    if (o < 4) {
        float h = b1[o];
        for (int e = 0; e < 64; ++e) h = fmaf(pl[e], w1[e * 4 + o], h);
        hid[o] = 0.5f * h * (1.f + erff(h * 0.70710678118654752f));  // exact gelu
    }
    __syncthreads();
    float sv = b2[o];
    #pragma unroll
    for (int hh = 0; hh < 4; ++hh) sv = fmaf(hid[hh], w2[hh * 64 + o], sv);
    s_out[b * 64 + o] = 1.f / (1.f + expf(-sv));
}

// K4: out = (x + interp(f)) * s + x
__global__ void k_apply(const float* __restrict__ x, const float* __restrict__ f,
                        const float* __restrict__ s, float* __restrict__ out)
{
    int gid = blockIdx.x * 256 + threadIdx.x;
    int o = gid & 63;
    int t = (gid >> 6) & 2047;
    int b = gid >> 17;
    float pos = fminf(fmaxf((t + 0.5f) * (2047.f / 2048.f) - 0.5f, 0.f), 2046.f);
    int   i0  = (int)pos;
    float w   = pos - (float)i0;
    int   i1  = min(i0 + 1, 2046);
    const float* fb = f + (size_t)b * (TM1 * 64);
    float fi = fb[i0 * 64 + o] * (1.f - w) + fb[i1 * 64 + o] * w;
    float xv = x[gid];
    float h1 = xv + fi;
    out[gid] = fmaf(h1, s[b * 64 + o], xv);
}

extern "C" void kernel_launch(void* const* d_in, const int* in_sizes, int n_in,
                              void* d_out, int out_size, void* d_ws, size_t ws_size,
                              hipStream_t stream)
{
    const float* x    = (const float*)d_in[0];
    const float* mask = (const float*)d_in[1];
    const float* Wd   = (const float*)d_in[2];
    const float* lng  = (const float*)d_in[3];
    const float* lnb  = (const float*)d_in[4];
    const float* pw   = (const float*)d_in[5];
    const float* pb   = (const float*)d_in[6];
    const float* sw1  = (const float*)d_in[7];
    const float* sb1  = (const float*)d_in[8];
    const float* sw2  = (const float*)d_in[9];
    const float* sb2  = (const float*)d_in[10];

    float* out    = (float*)d_out;
    float* f_ws   = (float*)d_ws;                 // 64*2047*64 = 33,538,048 floats
    float* pooled = f_ws + (size_t)B_ * TM1 * 64; // 4096
    float* denom  = pooled + 4096;                // 64
    float* s_ws   = denom + 64;                   // 4096

    hipMemsetAsync(pooled, 0, (4096 + 64) * sizeof(float), stream);

    hipLaunchKernelGGL(k_expm, dim3(2048), dim3(256), 0, stream,
                       x, mask, Wd, lng, lnb, pw, pb, f_ws);
    hipLaunchKernelGGL(k_pool, dim3(512), dim3(256), 0, stream,
                       x, mask, f_ws, pooled, denom);
    hipLaunchKernelGGL(k_se, dim3(64), dim3(64), 0, stream,
                       pooled, denom, sw1, sb1, sw2, sb2, s_ws);
    hipLaunchKernelGGL(k_apply, dim3(32768), dim3(256), 0, stream,
                       x, f_ws, s_ws, out);

    hipMemcpyAsync(out + (size_t)B_ * T_ * D_, mask,
                   (size_t)B_ * T_ * sizeof(float), hipMemcpyDeviceToDevice, stream);
}